// Round 1
// baseline (627.408 us; speedup 1.0000x reference)
//
#include <hip/hip_runtime.h>

// Problem constants
constexpr int BB = 8192;     // batch
constexpr int LL = 50;       // seq len
constexpr int DE = 128;      // emb dim
constexpr int DD = 392;      // total input dim
constexpr int HH1 = 256;
constexpr int HH2 = 128;
constexpr int EE = 4;
constexpr int TT = 2;

// ---------------------------------------------------------------------------
// K0: combine attention MLP weights.
// att_w1 is [512][64] (blocks: q | k | q-k | q*k).
// Wq' = W1q + W1qk ; Wk' = W1k - W1qk ; Wp = W1prod   (each [128][64])
// ---------------------------------------------------------------------------
__global__ __launch_bounds__(256) void prep_kernel(
    const float* __restrict__ w1,
    float* __restrict__ Wqp, float* __restrict__ Wkp, float* __restrict__ Wpp)
{
    int idx = blockIdx.x * 256 + threadIdx.x;  // 0..8191  (= d*64 + h)
    float q  = w1[idx];
    float k  = w1[idx + 8192];
    float qk = w1[idx + 16384];
    float p  = w1[idx + 24576];
    Wqp[idx] = q + qk;
    Wkp[idx] = k - qk;
    Wpp[idx] = p;
}

// ---------------------------------------------------------------------------
// K1: per-row DIN attention + concat + LayerNorm1 -> x0 [B][392]
// One 256-thread block per batch row.
// hidden[l][h] = qconst[h] + sum_d hist[l][d] * (Wk'[d][h] + q[d]*Wp[d][h])
// ---------------------------------------------------------------------------
__global__ __launch_bounds__(256) void attn_kernel(
    const int* __restrict__ userId, const int* __restrict__ movieId,
    const int* __restrict__ seq, const float* __restrict__ dense,
    const float* __restrict__ emb_user, const float* __restrict__ emb_movie,
    const float* __restrict__ Wqp, const float* __restrict__ Wkp,
    const float* __restrict__ Wpp,
    const float* __restrict__ att_b1, const float* __restrict__ att_w2,
    const float* __restrict__ att_b2,
    const float* __restrict__ in_gamma, const float* __restrict__ in_beta,
    float* __restrict__ x_out)
{
    __shared__ float hist[52][128];   // rows 50,51 zero-padded
    __shared__ float Vs[64 * 128];    // [h][slot^] xor-swizzled float4 slots
    __shared__ float qs[128];
    __shared__ int   seq_s[52];
    __shared__ float qconst[64];
    __shared__ float red[4][64];
    __shared__ float scores[52];
    __shared__ float probs[52];
    __shared__ float xrow[392];
    __shared__ float stats[2];

    const int b = blockIdx.x;
    const int t = threadIdx.x;
    const int lane = t & 63;
    const int w = t >> 6;

    if (t < 128) qs[t] = emb_movie[(long)movieId[b] * DE + t];
    if (t < 52)  seq_s[t] = (t < LL) ? seq[b * LL + t] : 0;
    __syncthreads();

    // stage hist [52][128] (f32, rows >= 50 zero)
    for (int idx = t; idx < 52 * 32; idx += 256) {
        int l = idx >> 5, dq = (idx & 31) << 2;
        float4 v = make_float4(0.f, 0.f, 0.f, 0.f);
        if (l < LL)
            v = *reinterpret_cast<const float4*>(&emb_movie[(long)seq_s[l] * DE + dq]);
        *reinterpret_cast<float4*>(&hist[l][dq]) = v;
    }

    // build per-row combined weight V (xor-swizzled so lane=h b128 reads are conflict-free)
    #pragma unroll
    for (int i = 0; i < 32; ++i) {
        int idx = t + (i << 8);
        int d = idx >> 6, h = idx & 63;
        float v = Wkp[idx] + qs[d] * Wpp[idx];
        Vs[h * 128 + (((d >> 2) ^ (h & 7)) << 2) + (d & 3)] = v;
    }

    // qconst[h] = b1[h] + sum_d q[d]*Wq'[d][h]   (4 waves x 32-d chunks)
    {
        float s = 0.f;
        const int d0 = w << 5;
        #pragma unroll
        for (int dd = 0; dd < 32; ++dd)
            s = fmaf(qs[d0 + dd], Wqp[(d0 + dd) * 64 + lane], s);
        red[w][lane] = s;
    }
    __syncthreads();
    if (t < 64) qconst[t] = att_b1[t] + red[0][t] + red[1][t] + red[2][t] + red[3][t];
    __syncthreads();

    // GEMM: hidden[l][h], lane = h, wave w owns l in [13w, 13w+13)
    float acc[13];
    #pragma unroll
    for (int j = 0; j < 13; ++j) acc[j] = 0.f;
    const int h = lane;
    const int lbase = w * 13;
    const int swz = (h & 7) << 2;
    for (int db = 0; db < 32; ++db) {
        const float4 v = *reinterpret_cast<const float4*>(&Vs[h * 128 + ((db << 2) ^ swz)]);
        #pragma unroll
        for (int j = 0; j < 13; ++j) {
            const float4 hv = *reinterpret_cast<const float4*>(&hist[lbase + j][db << 2]);
            acc[j] = fmaf(hv.x, v.x, fmaf(hv.y, v.y, fmaf(hv.z, v.z, fmaf(hv.w, v.w, acc[j]))));
        }
    }

    // scores[l] = b2 + sum_h relu(hidden)*w2[h]
    const float w2v = att_w2[h];
    const float b2v = att_b2[0];
    #pragma unroll
    for (int j = 0; j < 13; ++j) {
        float r = fmaxf(acc[j] + qconst[h], 0.f) * w2v;
        #pragma unroll
        for (int off = 32; off > 0; off >>= 1) r += __shfl_xor(r, off);
        const int l = lbase + j;
        if (lane == 0 && l < LL) scores[l] = r + b2v;
    }
    __syncthreads();

    // masked softmax over L (wave 0)
    if (w == 0) {
        const int l = lane;
        float s = (l < LL) ? (seq_s[l] > 0 ? scores[l] : -1e9f) : -INFINITY;
        float m = s;
        #pragma unroll
        for (int off = 32; off > 0; off >>= 1) m = fmaxf(m, __shfl_xor(m, off));
        float e = (l < LL) ? __expf(s - m) : 0.f;
        float sum = e;
        #pragma unroll
        for (int off = 32; off > 0; off >>= 1) sum += __shfl_xor(sum, off);
        if (l < LL) probs[l] = e / sum;
    }
    __syncthreads();

    // interest + assemble x row
    if (t < 128) {
        const int d = t;
        xrow[d] = emb_user[(long)userId[b] * DE + d];
        xrow[128 + d] = qs[d];
        float s = 0.f;
        #pragma unroll 5
        for (int l = 0; l < LL; ++l) s = fmaf(probs[l], hist[l][d], s);
        xrow[256 + d] = s;
        if (d < 8) xrow[384 + d] = dense[b * 8 + d];
    }
    __syncthreads();

    // LayerNorm over 392
    float v0 = xrow[t];
    float v1 = (t < 136) ? xrow[256 + t] : 0.f;
    float s = v0 + v1;
    float q2 = v0 * v0 + v1 * v1;
    #pragma unroll
    for (int off = 32; off > 0; off >>= 1) {
        s += __shfl_xor(s, off);
        q2 += __shfl_xor(q2, off);
    }
    if (lane == 0) { red[0][w] = s; red[1][w] = q2; }
    __syncthreads();
    if (t == 0) {
        float S = red[0][0] + red[0][1] + red[0][2] + red[0][3];
        float Q = red[1][0] + red[1][1] + red[1][2] + red[1][3];
        float mean = S / (float)DD;
        float var = Q / (float)DD - mean * mean;
        stats[0] = mean;
        stats[1] = rsqrtf(var + 1e-5f);
    }
    __syncthreads();
    const float mean = stats[0], inv = stats[1];
    const long base = (long)b * DD;
    x_out[base + t] = (v0 - mean) * inv * in_gamma[t] + in_beta[t];
    if (t < 136)
        x_out[base + 256 + t] = (v1 - mean) * inv * in_gamma[256 + t] + in_beta[256 + t];
}

// ---------------------------------------------------------------------------
// Generic f32 tiled GEMM: out = f(A[M,K] @ W[K,N] + bias)
// MODE 0: +bias ; MODE 1: relu(+bias) ; MODE 2: cross: out = x0*(acc+bias)+xin
// BM=BN=64, BK=16, 256 threads, 4x4 per thread. blockIdx.z strides pointers.
// ---------------------------------------------------------------------------
template<int MODE>
__global__ __launch_bounds__(256) void gemm_kernel(
    const float* __restrict__ A, const float* __restrict__ W,
    const float* __restrict__ bias, float* __restrict__ out,
    const float* __restrict__ x0, const float* __restrict__ xin,
    int M, int N, int K,
    long aZ, long wZ, long bZ, long oZ)
{
    __shared__ float As[16][68];
    __shared__ float Bs[16][68];
    const int z = blockIdx.z;
    A += (long)z * aZ; W += (long)z * wZ; bias += (long)z * bZ; out += (long)z * oZ;

    const int t = threadIdx.x;
    const int m0 = blockIdx.y * 64, n0 = blockIdx.x * 64;
    const int tm = t >> 4, tn = t & 15;
    const int lm = t >> 2, lk4 = (t & 3) << 2;   // A-load: row m0+lm, k = k0+lk4..+3
    const int lk = t >> 4, ln4 = (t & 15) << 2;  // B-load: k0+lk, n = n0+ln4..+3

    float acc[4][4];
    #pragma unroll
    for (int i = 0; i < 4; ++i)
        #pragma unroll
        for (int j = 0; j < 4; ++j) acc[i][j] = 0.f;

    for (int k0 = 0; k0 < K; k0 += 16) {
        float4 a = make_float4(0.f, 0.f, 0.f, 0.f);
        if (k0 + lk4 + 3 < K) {
            a = *reinterpret_cast<const float4*>(&A[(long)(m0 + lm) * K + k0 + lk4]);
        } else {
            float* ap = reinterpret_cast<float*>(&a);
            for (int j = 0; j < 4; ++j)
                if (k0 + lk4 + j < K) ap[j] = A[(long)(m0 + lm) * K + k0 + lk4 + j];
        }
        As[lk4 + 0][lm] = a.x; As[lk4 + 1][lm] = a.y;
        As[lk4 + 2][lm] = a.z; As[lk4 + 3][lm] = a.w;

        float4 bv = make_float4(0.f, 0.f, 0.f, 0.f);
        if (k0 + lk < K) {
            if (n0 + ln4 + 3 < N) {
                bv = *reinterpret_cast<const float4*>(&W[(long)(k0 + lk) * N + n0 + ln4]);
            } else {
                float* bp = reinterpret_cast<float*>(&bv);
                for (int j = 0; j < 4; ++j)
                    if (n0 + ln4 + j < N) bp[j] = W[(long)(k0 + lk) * N + n0 + ln4 + j];
            }
        }
        *reinterpret_cast<float4*>(&Bs[lk][ln4]) = bv;
        __syncthreads();

        #pragma unroll
        for (int kk = 0; kk < 16; ++kk) {
            float4 av = *reinterpret_cast<const float4*>(&As[kk][tm << 2]);
            float4 bw = *reinterpret_cast<const float4*>(&Bs[kk][tn << 2]);
            const float avx[4] = {av.x, av.y, av.z, av.w};
            const float bwx[4] = {bw.x, bw.y, bw.z, bw.w};
            #pragma unroll
            for (int i = 0; i < 4; ++i)
                #pragma unroll
                for (int j = 0; j < 4; ++j)
                    acc[i][j] = fmaf(avx[i], bwx[j], acc[i][j]);
        }
        __syncthreads();
    }

    #pragma unroll
    for (int i = 0; i < 4; ++i) {
        const int m = m0 + (tm << 2) + i;
        #pragma unroll
        for (int j = 0; j < 4; ++j) {
            const int n = n0 + (tn << 2) + j;
            if (n < N) {
                const long o = (long)m * N + n;
                float v = acc[i][j] + bias[n];
                if (MODE == 1) v = fmaxf(v, 0.f);
                if (MODE == 2) v = x0[o] * v + xin[o];
                out[o] = v;
            }
        }
    }
}

// ---------------------------------------------------------------------------
// K2: LayerNorm over 392 (block per row)
// ---------------------------------------------------------------------------
__global__ __launch_bounds__(256) void ln_kernel(
    const float* __restrict__ in,
    const float* __restrict__ gamma, const float* __restrict__ beta,
    float* __restrict__ out)
{
    __shared__ float red[2][4];
    __shared__ float stats[2];
    const int b = blockIdx.x, t = threadIdx.x, lane = t & 63, w = t >> 6;
    const long base = (long)b * DD;
    float v0 = in[base + t];
    float v1 = (t < 136) ? in[base + 256 + t] : 0.f;
    float s = v0 + v1;
    float q2 = v0 * v0 + v1 * v1;
    #pragma unroll
    for (int off = 32; off > 0; off >>= 1) {
        s += __shfl_xor(s, off);
        q2 += __shfl_xor(q2, off);
    }
    if (lane == 0) { red[0][w] = s; red[1][w] = q2; }
    __syncthreads();
    if (t == 0) {
        float S = red[0][0] + red[0][1] + red[0][2] + red[0][3];
        float Q = red[1][0] + red[1][1] + red[1][2] + red[1][3];
        float mean = S / (float)DD;
        float var = Q / (float)DD - mean * mean;
        stats[0] = mean;
        stats[1] = rsqrtf(var + 1e-5f);
    }
    __syncthreads();
    const float mean = stats[0], inv = stats[1];
    out[base + t] = (v0 - mean) * inv * gamma[t] + beta[t];
    if (t < 136)
        out[base + 256 + t] = (v1 - mean) * inv * gamma[256 + t] + beta[256 + t];
}

// ---------------------------------------------------------------------------
// K3: gates + expert mix + heads. One wave per row (4 rows / block).
// ---------------------------------------------------------------------------
__global__ __launch_bounds__(256) void final_kernel(
    const float* __restrict__ x, const float* __restrict__ eo,
    const float* __restrict__ gate_w, const float* __restrict__ gate_b,
    const float* __restrict__ head_w, const float* __restrict__ head_b,
    float* __restrict__ out)
{
    const int t = threadIdx.x, lane = t & 63, w = t >> 6;
    const int b = blockIdx.x * 4 + w;
    const float* xr = x + (long)b * DD;

    float xv[7];
    #pragma unroll
    for (int i = 0; i < 7; ++i) {
        int d = lane + (i << 6);
        xv[i] = (d < DD) ? xr[d] : 0.f;
    }

    // gate logits [t][e], 8 values
    float gl[8] = {0.f, 0.f, 0.f, 0.f, 0.f, 0.f, 0.f, 0.f};
    #pragma unroll
    for (int i = 0; i < 7; ++i) {
        int d = lane + (i << 6);
        if (d < DD) {
            float4 g0 = *reinterpret_cast<const float4*>(&gate_w[d << 2]);
            float4 g1 = *reinterpret_cast<const float4*>(&gate_w[1568 + (d << 2)]);
            gl[0] = fmaf(xv[i], g0.x, gl[0]); gl[1] = fmaf(xv[i], g0.y, gl[1]);
            gl[2] = fmaf(xv[i], g0.z, gl[2]); gl[3] = fmaf(xv[i], g0.w, gl[3]);
            gl[4] = fmaf(xv[i], g1.x, gl[4]); gl[5] = fmaf(xv[i], g1.y, gl[5]);
            gl[6] = fmaf(xv[i], g1.z, gl[6]); gl[7] = fmaf(xv[i], g1.w, gl[7]);
        }
    }
    #pragma unroll
    for (int v = 0; v < 8; ++v) {
        #pragma unroll
        for (int off = 32; off > 0; off >>= 1) gl[v] += __shfl_xor(gl[v], off);
    }

    // per-task softmax over 4 experts
    float g[2][4];
    #pragma unroll
    for (int tt = 0; tt < 2; ++tt) {
        float m = -1e30f;
        #pragma unroll
        for (int e = 0; e < 4; ++e) {
            gl[tt * 4 + e] += gate_b[tt * 4 + e];
            m = fmaxf(m, gl[tt * 4 + e]);
        }
        float sum = 0.f;
        #pragma unroll
        for (int e = 0; e < 4; ++e) { g[tt][e] = __expf(gl[tt * 4 + e] - m); sum += g[tt][e]; }
        #pragma unroll
        for (int e = 0; e < 4; ++e) g[tt][e] /= sum;
    }

    // eo . head_w per (t, e)
    float ed[8];
    #pragma unroll
    for (int e = 0; e < 4; ++e) {
        const float a = eo[(((long)e * BB) + b) * HH2 + lane];
        const float c = eo[(((long)e * BB) + b) * HH2 + 64 + lane];
        ed[e]     = fmaf(a, head_w[lane],       c * head_w[64 + lane]);
        ed[4 + e] = fmaf(a, head_w[128 + lane], c * head_w[192 + lane]);
    }
    #pragma unroll
    for (int v = 0; v < 8; ++v) {
        #pragma unroll
        for (int off = 32; off > 0; off >>= 1) ed[v] += __shfl_xor(ed[v], off);
    }

    if (lane == 0) {
        float l0 = head_b[0], l1 = head_b[1];
        #pragma unroll
        for (int e = 0; e < 4; ++e) {
            l0 = fmaf(g[0][e], ed[e], l0);
            l1 = fmaf(g[1][e], ed[4 + e], l1);
        }
        out[b] = l0;
        out[BB + b] = l1;
    }
}

// ---------------------------------------------------------------------------
extern "C" void kernel_launch(void* const* d_in, const int* in_sizes, int n_in,
                              void* d_out, int out_size, void* d_ws, size_t ws_size,
                              hipStream_t stream) {
    const int*   userId    = (const int*)d_in[0];
    const int*   movieId   = (const int*)d_in[1];
    const int*   seq       = (const int*)d_in[2];
    const float* dense     = (const float*)d_in[3];
    const float* emb_user  = (const float*)d_in[4];
    const float* emb_movie = (const float*)d_in[5];
    const float* att_w1    = (const float*)d_in[6];
    const float* att_b1    = (const float*)d_in[7];
    const float* att_w2    = (const float*)d_in[8];
    const float* att_b2    = (const float*)d_in[9];
    const float* in_gamma  = (const float*)d_in[10];
    const float* in_beta   = (const float*)d_in[11];
    const float* cr_gamma  = (const float*)d_in[12];
    const float* cr_beta   = (const float*)d_in[13];
    const float* cross_W   = (const float*)d_in[14];
    const float* cross_b   = (const float*)d_in[15];
    const float* exp_w1    = (const float*)d_in[16];
    const float* exp_b1    = (const float*)d_in[17];
    const float* exp_w2    = (const float*)d_in[18];
    const float* exp_b2    = (const float*)d_in[19];
    const float* gate_w    = (const float*)d_in[20];
    const float* gate_b    = (const float*)d_in[21];
    const float* head_w    = (const float*)d_in[22];
    const float* head_b    = (const float*)d_in[23];
    float* outp = (float*)d_out;

    float* ws = (float*)d_ws;
    float* Wqp = ws;
    float* Wkp = ws + 8192;
    float* Wpp = ws + 16384;
    float* x0  = ws + 24576;                 // [B][392]
    float* xA  = x0 + (long)BB * DD;         // [B][392]
    float* xB  = xA + (long)BB * DD;         // [B][392]
    float* h1  = xB + (long)BB * DD;         // [E][B][256]
    float* eo  = h1 + (long)BB * HH1 * EE;   // [E][B][128]

    // K0: weight prep
    prep_kernel<<<32, 256, 0, stream>>>(att_w1, Wqp, Wkp, Wpp);

    // K1: attention + concat + LN1 -> x0
    attn_kernel<<<BB, 256, 0, stream>>>(userId, movieId, seq, dense,
                                        emb_user, emb_movie, Wqp, Wkp, Wpp,
                                        att_b1, att_w2, att_b2,
                                        in_gamma, in_beta, x0);

    // CrossNetV2: x_{l+1} = x0 * (x_l W + b) + x_l
    dim3 gcross((DD + 63) / 64, BB / 64, 1);
    gemm_kernel<2><<<gcross, 256, 0, stream>>>(x0, cross_W,              cross_b,          xA,
                                               x0, x0, BB, DD, DD, 0, 0, 0, 0);
    gemm_kernel<2><<<gcross, 256, 0, stream>>>(xA, cross_W + 392 * 392,  cross_b + 392,    xB,
                                               x0, xA, BB, DD, DD, 0, 0, 0, 0);
    gemm_kernel<2><<<gcross, 256, 0, stream>>>(xB, cross_W + 2 * 392 * 392, cross_b + 784, xA,
                                               x0, xB, BB, DD, DD, 0, 0, 0, 0);

    // LN2: xA -> xB
    ln_kernel<<<BB, 256, 0, stream>>>(xA, cr_gamma, cr_beta, xB);

    // Experts: h1 = relu(x @ w1 + b1)  [E][B][256]
    dim3 ge1(HH1 / 64, BB / 64, EE);
    gemm_kernel<1><<<ge1, 256, 0, stream>>>(xB, exp_w1, exp_b1, h1,
                                            nullptr, nullptr, BB, HH1, DD,
                                            0, (long)DD * HH1, HH1, (long)BB * HH1);
    // eo = h1 @ w2 + b2  [E][B][128]
    dim3 ge2(HH2 / 64, BB / 64, EE);
    gemm_kernel<0><<<ge2, 256, 0, stream>>>(h1, exp_w2, exp_b2, eo,
                                            nullptr, nullptr, BB, HH2, HH1,
                                            (long)BB * HH1, (long)HH1 * HH2, HH2, (long)BB * HH2);

    // gates + mix + heads -> logits [2][B]
    final_kernel<<<BB / 4, 256, 0, stream>>>(xB, eo, gate_w, gate_b, head_w, head_b, outp);

    (void)in_sizes; (void)n_in; (void)out_size; (void)ws_size;
}

// Round 2
// 258.094 us; speedup vs baseline: 2.4309x; 2.4309x over previous
//
#include <hip/hip_runtime.h>

typedef short short8 __attribute__((ext_vector_type(8)));
typedef short short4v __attribute__((ext_vector_type(4)));
typedef float f32x4 __attribute__((ext_vector_type(4)));

constexpr int BB = 8192;   // batch
constexpr int LL = 50;     // seq len
constexpr int DE = 128;    // emb dim
constexpr int DD = 392;    // total input dim
constexpr int HH1 = 256;
constexpr int HH2 = 128;

__device__ __forceinline__ short f2b(float x) {
    unsigned u = __builtin_bit_cast(unsigned, x);
    u = (u + 0x7fff + ((u >> 16) & 1)) >> 16;   // RNE
    return (short)u;
}
__device__ __forceinline__ float b2f(short v) {
    unsigned u = ((unsigned)(unsigned short)v) << 16;
    return __builtin_bit_cast(float, u);
}

// ---------------------------------------------------------------------------
// prep: Wq' = W1q + W1(q-k) rows  (f32, [128][64])
// ---------------------------------------------------------------------------
__global__ __launch_bounds__(256) void prep_wqp(const float* __restrict__ w1,
                                                float* __restrict__ Wqp) {
    int idx = blockIdx.x * 256 + threadIdx.x;       // d*64+h, 8192
    Wqp[idx] = w1[idx] + w1[idx + 16384];
}

// ---------------------------------------------------------------------------
// prep: combined B weight Wc[256][64] (k<128: Wk'=W1k-W1d ; k>=128: Wp),
// stored bf16 in MFMA B-fragment order: WcF[kt(8)][nt(4)][lane(64)][e(8)]
// frag element (lane,e) = Wc[kt*32 + (lane>>4)*8 + e][nt*16 + (lane&15)]
// ---------------------------------------------------------------------------
__global__ __launch_bounds__(256) void prep_wcf(const float* __restrict__ w1,
                                                short* __restrict__ WcF) {
    int o = blockIdx.x * 256 + threadIdx.x;         // 16384
    int e = o & 7, lidx = (o >> 3) & 63, nt = (o >> 9) & 3, kt = o >> 11;
    int k = kt * 32 + ((lidx >> 4) << 3) + e;
    int h = (nt << 4) + (lidx & 15);
    float v;
    if (k < 128) v = w1[(128 + k) * 64 + h] - w1[(256 + k) * 64 + h];
    else         v = w1[(384 + (k - 128)) * 64 + h];
    WcF[o] = f2b(v);
}

// ---------------------------------------------------------------------------
// transpose+convert: out[z][c][r] = bf16(in[z][r][c])
// ---------------------------------------------------------------------------
__global__ __launch_bounds__(256) void trans_kernel(const float* __restrict__ in,
                                                    short* __restrict__ out,
                                                    int R, int C) {
    long zo = (long)blockIdx.y * R * C;
    int idx = blockIdx.x * 256 + threadIdx.x;
    if (idx >= R * C) return;
    int c = idx / R, r = idx - c * R;
    out[zo + idx] = f2b(in[zo + (long)r * C + c]);
}

// ---------------------------------------------------------------------------
// K1: DIN attention (MFMA) + concat + LayerNorm1 -> x0 (f32 + bf16)
// A = [hist | hist*q] (64x256 bf16, rows>=50 zero), B = WcF (frag-order regs)
// ---------------------------------------------------------------------------
__global__ __launch_bounds__(256) void attn_kernel(
    const int* __restrict__ userId, const int* __restrict__ movieId,
    const int* __restrict__ seq, const float* __restrict__ dense,
    const float* __restrict__ emb_user, const float* __restrict__ emb_movie,
    const float* __restrict__ Wqp, const short* __restrict__ WcF,
    const float* __restrict__ att_b1, const float* __restrict__ att_w2,
    const float* __restrict__ att_b2,
    const float* __restrict__ in_gamma, const float* __restrict__ in_beta,
    float* __restrict__ x0f, short* __restrict__ x0b)
{
    __shared__ short hist[64 * 128];    // swizzled: byte = l*256 + ((d*2)^((l&7)<<4))
    __shared__ short histq[64 * 128];
    __shared__ float qs[128];
    __shared__ int   seq_s[64];
    __shared__ float qconst[64];
    __shared__ float sp[4][64];
    __shared__ float probs[64];
    __shared__ float xrow[392];
    __shared__ float stats[2];

    const int b = blockIdx.x;
    const int t = threadIdx.x;
    const int lane = t & 63;
    const int w = t >> 6;

    if (t < 128) qs[t] = emb_movie[(long)movieId[b] * DE + t];
    if (t < 64)  seq_s[t] = (t < LL) ? seq[b * LL + t] : 0;
    __syncthreads();

    // stage hist & histq (bf16, swizzled), rows >= LL zero
    for (int i = 0; i < 8; ++i) {
        int idx = t + (i << 8);
        int l = idx >> 5, d0 = (idx & 31) << 2;
        float4 v = make_float4(0.f, 0.f, 0.f, 0.f);
        if (l < LL)
            v = *reinterpret_cast<const float4*>(&emb_movie[(long)seq_s[l] * DE + d0]);
        short4v hv, qv;
        hv[0] = f2b(v.x); hv[1] = f2b(v.y); hv[2] = f2b(v.z); hv[3] = f2b(v.w);
        qv[0] = f2b(v.x * qs[d0]);     qv[1] = f2b(v.y * qs[d0 + 1]);
        qv[2] = f2b(v.z * qs[d0 + 2]); qv[3] = f2b(v.w * qs[d0 + 3]);
        int byte = (l << 8) + (((d0 << 1)) ^ ((l & 7) << 4));
        *reinterpret_cast<short4v*>(reinterpret_cast<char*>(hist) + byte) = hv;
        *reinterpret_cast<short4v*>(reinterpret_cast<char*>(histq) + byte) = qv;
    }

    // qconst partial: wave w covers d in [32w, 32w+32)
    {
        float s = 0.f;
        const int d0 = w << 5;
        #pragma unroll
        for (int dd = 0; dd < 32; ++dd)
            s = fmaf(qs[d0 + dd], Wqp[(d0 + dd) * 64 + lane], s);
        sp[w][lane] = s;
    }

    // B fragments from global (frag-ordered, wave w -> n-tile w)
    short8 bfrag[8];
    #pragma unroll
    for (int kt = 0; kt < 8; ++kt)
        bfrag[kt] = *reinterpret_cast<const short8*>(&WcF[(((kt << 2) + w) << 6 | lane) << 3]);

    __syncthreads();
    if (t < 64) qconst[t] = att_b1[t] + sp[0][t] + sp[1][t] + sp[2][t] + sp[3][t];
    __syncthreads();

    // MFMA: acc[mt] = A(64x256) @ Wc(256x64), wave w owns cols w*16..+15
    f32x4 acc[4];
    #pragma unroll
    for (int mt = 0; mt < 4; ++mt) {
        #pragma unroll
        for (int r = 0; r < 4; ++r) acc[mt][r] = 0.f;
    }
    #pragma unroll
    for (int mt = 0; mt < 4; ++mt) {
        const int row = (mt << 4) + (lane & 15);
        const int rbase = (row << 8);
        const int swz = (row & 7) << 4;
        #pragma unroll
        for (int kt = 0; kt < 8; ++kt) {
            const char* src = reinterpret_cast<const char*>((kt < 4) ? hist : histq);
            int kbyte = ((kt & 3) << 6) + ((lane >> 4) << 4);
            short8 a = *reinterpret_cast<const short8*>(src + rbase + (kbyte ^ swz));
            acc[mt] = __builtin_amdgcn_mfma_f32_16x16x32_bf16(a, bfrag[kt], acc[mt], 0, 0, 0);
        }
    }

    // scores: relu(hidden + qconst) . w2, reduce over h
    {
        const int hcol = (w << 4) + (lane & 15);
        const float qc = qconst[hcol];
        const float w2v = att_w2[hcol];
        #pragma unroll
        for (int mt = 0; mt < 4; ++mt) {
            #pragma unroll
            for (int r = 0; r < 4; ++r) {
                float v = fmaxf(acc[mt][r] + qc, 0.f) * w2v;
                v += __shfl_xor(v, 1); v += __shfl_xor(v, 2);
                v += __shfl_xor(v, 4); v += __shfl_xor(v, 8);
                if ((lane & 15) == 0)
                    sp[w][(mt << 4) + ((lane >> 4) << 2) + r] = v;
            }
        }
    }
    __syncthreads();

    // softmax over l (wave 0)
    if (t < 64) {
        float sc = sp[0][t] + sp[1][t] + sp[2][t] + sp[3][t] + att_b2[0];
        float s = (t < LL) ? ((seq_s[t] > 0) ? sc : -1e9f) : -INFINITY;
        float m = s;
        #pragma unroll
        for (int off = 32; off > 0; off >>= 1) m = fmaxf(m, __shfl_xor(m, off));
        float e = (t < LL) ? __expf(s - m) : 0.f;
        float sum = e;
        #pragma unroll
        for (int off = 32; off > 0; off >>= 1) sum += __shfl_xor(sum, off);
        if (t < LL) probs[t] = e / sum;
    }
    __syncthreads();

    // interest (f32 re-gather, L1-hot) + assemble x row
    if (t < 128) {
        const int d = t;
        float s = 0.f;
        #pragma unroll 10
        for (int l = 0; l < LL; ++l)
            s = fmaf(probs[l], emb_movie[(long)seq_s[l] * DE + d], s);
        xrow[256 + d] = s;
        xrow[d] = emb_user[(long)userId[b] * DE + d];
        xrow[128 + d] = qs[d];
        if (d < 8) xrow[384 + d] = dense[b * 8 + d];
    }
    __syncthreads();

    // LayerNorm over 392
    float v0 = xrow[t];
    float v1 = (t < 136) ? xrow[256 + t] : 0.f;
    float s2 = v0 + v1, q2 = v0 * v0 + v1 * v1;
    #pragma unroll
    for (int off = 32; off > 0; off >>= 1) {
        s2 += __shfl_xor(s2, off);
        q2 += __shfl_xor(q2, off);
    }
    if (lane == 0) { sp[0][w] = s2; sp[1][w] = q2; }
    __syncthreads();
    if (t == 0) {
        float S = sp[0][0] + sp[0][1] + sp[0][2] + sp[0][3];
        float Q = sp[1][0] + sp[1][1] + sp[1][2] + sp[1][3];
        float mean = S / (float)DD;
        float var = Q / (float)DD - mean * mean;
        stats[0] = mean;
        stats[1] = rsqrtf(var + 1e-5f);
    }
    __syncthreads();
    const float mean = stats[0], inv = stats[1];
    const long base = (long)b * DD;
    float o0 = (v0 - mean) * inv * in_gamma[t] + in_beta[t];
    x0f[base + t] = o0; x0b[base + t] = f2b(o0);
    if (t < 136) {
        float o1 = (v1 - mean) * inv * in_gamma[256 + t] + in_beta[256 + t];
        x0f[base + 256 + t] = o1; x0b[base + 256 + t] = f2b(o1);
    }
}

// ---------------------------------------------------------------------------
// Generic bf16 MFMA GEMM: out = f(A[M,K](bf16) @ WT[N,K]^T(bf16) + bias)
// MODE 0: +bias ; 1: relu(+bias) ; 2: cross: out = x0*(acc+bias)+xin
// 64x64 tile, BK=64, 256 threads, wave w -> m-subtile w; z strides operands.
// ---------------------------------------------------------------------------
template<int MODE, int WF32, int WB16>
__global__ __launch_bounds__(256) void bgemm(
    const short* __restrict__ A, const short* __restrict__ WT,
    const float* __restrict__ bias,
    float* __restrict__ outF, short* __restrict__ outB,
    const float* __restrict__ x0, const float* __restrict__ xin,
    int M, int N, int K, long aZ, long wZ, long bZ, long oZ)
{
    __shared__ short As[64 * 64];   // swizzled: byte = r*128 + ((k*2)^((r&7)<<4))
    __shared__ short Bs[64 * 64];
    const int z = blockIdx.z;
    A += (long)z * aZ; WT += (long)z * wZ; bias += (long)z * bZ;
    const long oz = (long)z * oZ;

    const int t = threadIdx.x, w = t >> 6, lane = t & 63;
    const int m0 = blockIdx.y * 64, n0 = blockIdx.x * 64;
    const int sm = t >> 3, sk8 = (t & 7) << 3;   // staging: row, k-offset

    f32x4 acc[4];
    #pragma unroll
    for (int i = 0; i < 4; ++i) {
        #pragma unroll
        for (int r = 0; r < 4; ++r) acc[i][r] = 0.f;
    }

    for (int k0 = 0; k0 < K; k0 += 64) {
        #pragma unroll
        for (int i = 0; i < 2; ++i) {
            const int r = sm + i * 32;
            const int byte = (r << 7) + (((sk8 << 1)) ^ ((r & 7) << 4));
            short8 av = {0, 0, 0, 0, 0, 0, 0, 0};
            if (k0 + sk8 < K)
                av = *reinterpret_cast<const short8*>(&A[(long)(m0 + r) * K + k0 + sk8]);
            *reinterpret_cast<short8*>(reinterpret_cast<char*>(As) + byte) = av;
            short8 bv = {0, 0, 0, 0, 0, 0, 0, 0};
            if (n0 + r < N && k0 + sk8 < K)
                bv = *reinterpret_cast<const short8*>(&WT[(long)(n0 + r) * K + k0 + sk8]);
            *reinterpret_cast<short8*>(reinterpret_cast<char*>(Bs) + byte) = bv;
        }
        __syncthreads();

        #pragma unroll
        for (int kt = 0; kt < 2; ++kt) {
            const int kbyte = (kt << 6) + ((lane >> 4) << 4);
            const int ar = (w << 4) + (lane & 15);
            short8 a = *reinterpret_cast<const short8*>(
                reinterpret_cast<char*>(As) + (ar << 7) + (kbyte ^ ((ar & 7) << 4)));
            #pragma unroll
            for (int nt = 0; nt < 4; ++nt) {
                const int br = (nt << 4) + (lane & 15);
                short8 bb = *reinterpret_cast<const short8*>(
                    reinterpret_cast<char*>(Bs) + (br << 7) + (kbyte ^ ((br & 7) << 4)));
                acc[nt] = __builtin_amdgcn_mfma_f32_16x16x32_bf16(a, bb, acc[nt], 0, 0, 0);
            }
        }
        __syncthreads();
    }

    #pragma unroll
    for (int nt = 0; nt < 4; ++nt) {
        const int col = n0 + (nt << 4) + (lane & 15);
        if (col < N) {
            const float bv = bias[col];
            #pragma unroll
            for (int r = 0; r < 4; ++r) {
                const int row = m0 + (w << 4) + ((lane >> 4) << 2) + r;
                float v = acc[nt][r] + bv;
                if (MODE == 1) v = fmaxf(v, 0.f);
                const long o = (long)row * N + col;
                if (MODE == 2) v = x0[o] * v + xin[o];
                if (WF32) outF[oz + o] = v;
                if (WB16) outB[oz + o] = f2b(v);
            }
        }
    }
}

// ---------------------------------------------------------------------------
// LayerNorm over 392 (block per row), f32 + bf16 outputs
// ---------------------------------------------------------------------------
__global__ __launch_bounds__(256) void ln_kernel(
    const float* __restrict__ in,
    const float* __restrict__ gamma, const float* __restrict__ beta,
    float* __restrict__ outF, short* __restrict__ outB)
{
    __shared__ float red[2][4];
    __shared__ float stats[2];
    const int b = blockIdx.x, t = threadIdx.x, lane = t & 63, w = t >> 6;
    const long base = (long)b * DD;
    float v0 = in[base + t];
    float v1 = (t < 136) ? in[base + 256 + t] : 0.f;
    float s = v0 + v1, q2 = v0 * v0 + v1 * v1;
    #pragma unroll
    for (int off = 32; off > 0; off >>= 1) {
        s += __shfl_xor(s, off);
        q2 += __shfl_xor(q2, off);
    }
    if (lane == 0) { red[0][w] = s; red[1][w] = q2; }
    __syncthreads();
    if (t == 0) {
        float S = red[0][0] + red[0][1] + red[0][2] + red[0][3];
        float Q = red[1][0] + red[1][1] + red[1][2] + red[1][3];
        float mean = S / (float)DD;
        float var = Q / (float)DD - mean * mean;
        stats[0] = mean;
        stats[1] = rsqrtf(var + 1e-5f);
    }
    __syncthreads();
    const float mean = stats[0], inv = stats[1];
    float o0 = (v0 - mean) * inv * gamma[t] + beta[t];
    outF[base + t] = o0; outB[base + t] = f2b(o0);
    if (t < 136) {
        float o1 = (v1 - mean) * inv * gamma[256 + t] + beta[256 + t];
        outF[base + 256 + t] = o1; outB[base + 256 + t] = f2b(o1);
    }
}

// ---------------------------------------------------------------------------
// K3: gates + expert mix + heads. One wave per row (4 rows / block).
// ---------------------------------------------------------------------------
__global__ __launch_bounds__(256) void final_kernel(
    const float* __restrict__ x, const float* __restrict__ eo,
    const float* __restrict__ gate_w, const float* __restrict__ gate_b,
    const float* __restrict__ head_w, const float* __restrict__ head_b,
    float* __restrict__ out)
{
    const int t = threadIdx.x, lane = t & 63, w = t >> 6;
    const int b = blockIdx.x * 4 + w;
    const float* xr = x + (long)b * DD;

    float xv[7];
    #pragma unroll
    for (int i = 0; i < 7; ++i) {
        int d = lane + (i << 6);
        xv[i] = (d < DD) ? xr[d] : 0.f;
    }

    float gl[8] = {0.f, 0.f, 0.f, 0.f, 0.f, 0.f, 0.f, 0.f};
    #pragma unroll
    for (int i = 0; i < 7; ++i) {
        int d = lane + (i << 6);
        if (d < DD) {
            float4 g0 = *reinterpret_cast<const float4*>(&gate_w[d << 2]);
            float4 g1 = *reinterpret_cast<const float4*>(&gate_w[1568 + (d << 2)]);
            gl[0] = fmaf(xv[i], g0.x, gl[0]); gl[1] = fmaf(xv[i], g0.y, gl[1]);
            gl[2] = fmaf(xv[i], g0.z, gl[2]); gl[3] = fmaf(xv[i], g0.w, gl[3]);
            gl[4] = fmaf(xv[i], g1.x, gl[4]); gl[5] = fmaf(xv[i], g1.y, gl[5]);
            gl[6] = fmaf(xv[i], g1.z, gl[6]); gl[7] = fmaf(xv[i], g1.w, gl[7]);
        }
    }
    #pragma unroll
    for (int v = 0; v < 8; ++v) {
        #pragma unroll
        for (int off = 32; off > 0; off >>= 1) gl[v] += __shfl_xor(gl[v], off);
    }

    float g[2][4];
    #pragma unroll
    for (int tt = 0; tt < 2; ++tt) {
        float m = -1e30f;
        #pragma unroll
        for (int e = 0; e < 4; ++e) {
            gl[tt * 4 + e] += gate_b[tt * 4 + e];
            m = fmaxf(m, gl[tt * 4 + e]);
        }
        float sum = 0.f;
        #pragma unroll
        for (int e = 0; e < 4; ++e) { g[tt][e] = __expf(gl[tt * 4 + e] - m); sum += g[tt][e]; }
        #pragma unroll
        for (int e = 0; e < 4; ++e) g[tt][e] /= sum;
    }

    float ed[8];
    #pragma unroll
    for (int e = 0; e < 4; ++e) {
        const float a = eo[(((long)e * BB) + b) * HH2 + lane];
        const float c = eo[(((long)e * BB) + b) * HH2 + 64 + lane];
        ed[e]     = fmaf(a, head_w[lane],       c * head_w[64 + lane]);
        ed[4 + e] = fmaf(a, head_w[128 + lane], c * head_w[192 + lane]);
    }
    #pragma unroll
    for (int v = 0; v < 8; ++v) {
        #pragma unroll
        for (int off = 32; off > 0; off >>= 1) ed[v] += __shfl_xor(ed[v], off);
    }

    if (lane == 0) {
        float l0 = head_b[0], l1 = head_b[1];
        #pragma unroll
        for (int e = 0; e < 4; ++e) {
            l0 = fmaf(g[0][e], ed[e], l0);
            l1 = fmaf(g[1][e], ed[4 + e], l1);
        }
        out[b] = l0;
        out[BB + b] = l1;
    }
}

// ---------------------------------------------------------------------------
extern "C" void kernel_launch(void* const* d_in, const int* in_sizes, int n_in,
                              void* d_out, int out_size, void* d_ws, size_t ws_size,
                              hipStream_t stream) {
    const int*   userId    = (const int*)d_in[0];
    const int*   movieId   = (const int*)d_in[1];
    const int*   seq       = (const int*)d_in[2];
    const float* dense     = (const float*)d_in[3];
    const float* emb_user  = (const float*)d_in[4];
    const float* emb_movie = (const float*)d_in[5];
    const float* att_w1    = (const float*)d_in[6];
    const float* att_b1    = (const float*)d_in[7];
    const float* att_w2    = (const float*)d_in[8];
    const float* att_b2    = (const float*)d_in[9];
    const float* in_gamma  = (const float*)d_in[10];
    const float* in_beta   = (const float*)d_in[11];
    const float* cr_gamma  = (const float*)d_in[12];
    const float* cr_beta   = (const float*)d_in[13];
    const float* cross_W   = (const float*)d_in[14];
    const float* cross_b   = (const float*)d_in[15];
    const float* exp_w1    = (const float*)d_in[16];
    const float* exp_b1    = (const float*)d_in[17];
    const float* exp_w2    = (const float*)d_in[18];
    const float* exp_b2    = (const float*)d_in[19];
    const float* gate_w    = (const float*)d_in[20];
    const float* gate_b    = (const float*)d_in[21];
    const float* head_w    = (const float*)d_in[22];
    const float* head_b    = (const float*)d_in[23];
    float* outp = (float*)d_out;

    char* p = (char*)d_ws;
    auto alloc = [&](size_t bytes) -> char* {
        char* r = p; p += (bytes + 255) & ~(size_t)255; return r;
    };
    float* Wqp = (float*)alloc(8192 * 4);
    short* WcF = (short*)alloc(16384 * 2);
    short* WTc = (short*)alloc((size_t)3 * 392 * 392 * 2);
    short* WT1 = (short*)alloc((size_t)4 * 256 * 392 * 2);
    short* WT2 = (short*)alloc((size_t)4 * 128 * 256 * 2);
    float* x0f = (float*)alloc((size_t)BB * DD * 4);
    short* x0b = (short*)alloc((size_t)BB * DD * 2);
    float* xAf = (float*)alloc((size_t)BB * DD * 4);
    short* xAb = (short*)alloc((size_t)BB * DD * 2);
    float* xBf = (float*)alloc((size_t)BB * DD * 4);
    short* xBb = (short*)alloc((size_t)BB * DD * 2);
    short* h1b = (short*)alloc((size_t)4 * BB * HH1 * 2);
    float* eo  = (float*)alloc((size_t)4 * BB * HH2 * 4);

    prep_wqp<<<32, 256, 0, stream>>>(att_w1, Wqp);
    prep_wcf<<<64, 256, 0, stream>>>(att_w1, WcF);
    trans_kernel<<<dim3((392 * 392 + 255) / 256, 3), 256, 0, stream>>>(cross_W, WTc, 392, 392);
    trans_kernel<<<dim3((392 * 256 + 255) / 256, 4), 256, 0, stream>>>(exp_w1, WT1, 392, 256);
    trans_kernel<<<dim3((256 * 128 + 255) / 256, 4), 256, 0, stream>>>(exp_w2, WT2, 256, 128);

    attn_kernel<<<BB, 256, 0, stream>>>(userId, movieId, seq, dense,
                                        emb_user, emb_movie, Wqp, WcF,
                                        att_b1, att_w2, att_b2,
                                        in_gamma, in_beta, x0f, x0b);

    // CrossNetV2
    dim3 gc(7, BB / 64, 1);
    bgemm<2, 1, 1><<<gc, 256, 0, stream>>>(x0b, WTc, cross_b, xAf, xAb,
                                           x0f, x0f, BB, DD, DD, 0, 0, 0, 0);
    bgemm<2, 1, 1><<<gc, 256, 0, stream>>>(xAb, WTc + 392 * 392, cross_b + 392, xBf, xBb,
                                           x0f, xAf, BB, DD, DD, 0, 0, 0, 0);
    bgemm<2, 1, 0><<<gc, 256, 0, stream>>>(xBb, WTc + 2 * 392 * 392, cross_b + 784, xAf, nullptr,
                                           x0f, xBf, BB, DD, DD, 0, 0, 0, 0);

    // LN2: xAf -> xBf (+bf16)
    ln_kernel<<<BB, 256, 0, stream>>>(xAf, cr_gamma, cr_beta, xBf, xBb);

    // Experts
    bgemm<1, 0, 1><<<dim3(HH1 / 64, BB / 64, 4), 256, 0, stream>>>(
        xBb, WT1, exp_b1, nullptr, h1b, nullptr, nullptr,
        BB, HH1, DD, 0, (long)HH1 * DD, HH1, (long)BB * HH1);
    bgemm<0, 1, 0><<<dim3(HH2 / 64, BB / 64, 4), 256, 0, stream>>>(
        h1b, WT2, exp_b2, eo, nullptr, nullptr, nullptr,
        BB, HH2, HH1, (long)BB * HH1, (long)HH2 * HH1, HH2, (long)BB * HH2);

    final_kernel<<<BB / 4, 256, 0, stream>>>(xBf, eo, gate_w, gate_b, head_w, head_b, outp);

    (void)in_sizes; (void)n_in; (void)out_size; (void)ws_size;
}

// Round 3
// 228.380 us; speedup vs baseline: 2.7472x; 1.1301x over previous
//
#include <hip/hip_runtime.h>
#include <hip/hip_bf16.h>

typedef short short8 __attribute__((ext_vector_type(8)));
typedef short short4v __attribute__((ext_vector_type(4)));
typedef float f32x4 __attribute__((ext_vector_type(4)));

constexpr int BB = 8192;   // batch
constexpr int LL = 50;     // seq len
constexpr int DE = 128;    // emb dim
constexpr int DD = 392;    // total input dim
constexpr int HH1 = 256;
constexpr int HH2 = 128;

__device__ __forceinline__ short f2b(float x) {
    __hip_bfloat16 h = __float2bfloat16(x);   // RNE, compiler emits v_cvt_pk_bf16_f32
    return __builtin_bit_cast(short, h);
}
__device__ __forceinline__ float b2f(short v) {
    unsigned u = ((unsigned)(unsigned short)v) << 16;
    return __builtin_bit_cast(float, u);
}

// ---------------------------------------------------------------------------
// prep: Wq' = W1q + W1(q-k)  (f32, [128][64])
// ---------------------------------------------------------------------------
__global__ __launch_bounds__(256) void prep_wqp(const float* __restrict__ w1,
                                                float* __restrict__ Wqp) {
    int idx = blockIdx.x * 256 + threadIdx.x;       // d*64+h, 8192
    Wqp[idx] = w1[idx] + w1[idx + 16384];
}

// ---------------------------------------------------------------------------
// prep: Wk' = W1k - W1d and Wp, both f32 in MFMA B-fragment order:
// o = [kt(4)][nt(4)][lane(64)][e(8)]; element = W[k][h],
// k = kt*32 + (lane>>4)*8 + e, h = nt*16 + (lane&15)
// ---------------------------------------------------------------------------
__global__ __launch_bounds__(256) void prep_wkwp(const float* __restrict__ w1,
                                                 float* __restrict__ WkF,
                                                 float* __restrict__ WpF) {
    int o = blockIdx.x * 256 + threadIdx.x;         // 8192
    int e = o & 7, lane = (o >> 3) & 63, nt = (o >> 9) & 3, kt = o >> 11;
    int k = (kt << 5) + ((lane >> 4) << 3) + e;
    int h = (nt << 4) + (lane & 15);
    WkF[o] = w1[(128 + k) * 64 + h] - w1[(256 + k) * 64 + h];
    WpF[o] = w1[(384 + k) * 64 + h];
}

// ---------------------------------------------------------------------------
// transpose+convert: out[z][c][r] = bf16(in[z][r][c])
// ---------------------------------------------------------------------------
__global__ __launch_bounds__(256) void trans_kernel(const float* __restrict__ in,
                                                    short* __restrict__ out,
                                                    int R, int C) {
    long zo = (long)blockIdx.y * R * C;
    int idx = blockIdx.x * 256 + threadIdx.x;
    if (idx >= R * C) return;
    int c = idx / R, r = idx - c * R;
    out[zo + idx] = f2b(in[zo + (long)r * C + c]);
}

// ---------------------------------------------------------------------------
// prep: hw2[e][k][t] = sum_o exp_w2[e][k][o] * head_w[t][o]  (4*256*2 f32)
//       hc[e][t]     = sum_o exp_b2[e][o] * head_w[t][o]
// ---------------------------------------------------------------------------
__global__ __launch_bounds__(256) void prep_hw2(const float* __restrict__ w2,
                                                const float* __restrict__ b2,
                                                const float* __restrict__ head_w,
                                                float* __restrict__ hw2,
                                                float* __restrict__ hc) {
    __shared__ float hw[256];
    const int e = blockIdx.x, t = threadIdx.x;
    hw[t] = head_w[t];
    __syncthreads();
    const float* row = &w2[((long)e * HH1 + t) * HH2];
    float s0 = 0.f, s1 = 0.f;
    #pragma unroll 8
    for (int o = 0; o < 128; o += 4) {
        float4 v = *reinterpret_cast<const float4*>(&row[o]);
        s0 += v.x * hw[o] + v.y * hw[o + 1] + v.z * hw[o + 2] + v.w * hw[o + 3];
        s1 += v.x * hw[128 + o] + v.y * hw[129 + o] + v.z * hw[130 + o] + v.w * hw[131 + o];
    }
    hw2[(((e << 8) + t) << 1) + 0] = s0;
    hw2[(((e << 8) + t) << 1) + 1] = s1;
    if (t < 2) {
        float s = 0.f;
        for (int o = 0; o < 128; ++o) s += b2[e * 128 + o] * hw[t * 128 + o];
        hc[e * 2 + t] = s;
    }
}

// ---------------------------------------------------------------------------
// K1: DIN attention (MFMA, q folded into B) + concat + LayerNorm1 -> x0
// hidden[l][h] = qconst[h] + sum_k hist[l][k] * (Wk'[k][h] + q[k]*Wp[k][h])
// A = hist (64x128 bf16 LDS, swizzled); B = V built per-row in frag registers.
// ---------------------------------------------------------------------------
__global__ __launch_bounds__(256, 8) void attn_kernel(
    const int* __restrict__ userId, const int* __restrict__ movieId,
    const int* __restrict__ seq, const float* __restrict__ dense,
    const float* __restrict__ emb_user, const float* __restrict__ emb_movie,
    const float* __restrict__ Wqp, const float* __restrict__ WkF,
    const float* __restrict__ WpF,
    const float* __restrict__ att_b1, const float* __restrict__ att_w2,
    const float* __restrict__ att_b2,
    const float* __restrict__ in_gamma, const float* __restrict__ in_beta,
    float* __restrict__ x0f, short* __restrict__ x0b)
{
    __shared__ short hist[64 * 128];    // swizzled: byte = l*256 + ((d*2)^((l&7)<<4))
    __shared__ float qs[128];
    __shared__ int   seq_s[64];
    __shared__ float qconst[64];
    __shared__ float sp[4][64];         // reused: qconst partials / score partials / interest / LN
    __shared__ float probs[64];
    __shared__ float xrow[392];
    __shared__ float stats[2];

    const int b = blockIdx.x;
    const int t = threadIdx.x;
    const int lane = t & 63;
    const int w = t >> 6;

    if (t < 128) qs[t] = emb_movie[(long)movieId[b] * DE + t];
    if (t < 64)  seq_s[t] = (t < LL) ? seq[b * LL + t] : 0;
    __syncthreads();   // A: qs/seq_s ready

    // stage hist bf16 swizzled (rows >= LL zero)
    #pragma unroll
    for (int i = 0; i < 8; ++i) {
        int idx = t + (i << 8);
        int l = idx >> 5, d0 = (idx & 31) << 2;
        float4 v = make_float4(0.f, 0.f, 0.f, 0.f);
        if (l < LL)
            v = *reinterpret_cast<const float4*>(&emb_movie[(long)seq_s[l] * DE + d0]);
        short4v hv;
        hv[0] = f2b(v.x); hv[1] = f2b(v.y); hv[2] = f2b(v.z); hv[3] = f2b(v.w);
        int byte = (l << 8) + ((d0 << 1) ^ ((l & 7) << 4));
        *reinterpret_cast<short4v*>(reinterpret_cast<char*>(hist) + byte) = hv;
    }

    // build per-row B fragments: V[k][h] = Wk'[k][h] + q[k]*Wp[k][h]
    short8 bfrag[4];
    #pragma unroll
    for (int kt = 0; kt < 4; ++kt) {
        const int fo = ((((kt << 2) + w) << 6) | lane) << 3;
        float4 wk0 = *reinterpret_cast<const float4*>(&WkF[fo]);
        float4 wk1 = *reinterpret_cast<const float4*>(&WkF[fo + 4]);
        float4 wp0 = *reinterpret_cast<const float4*>(&WpF[fo]);
        float4 wp1 = *reinterpret_cast<const float4*>(&WpF[fo + 4]);
        const int kq = (kt << 5) + ((lane >> 4) << 3);
        float4 q0 = *reinterpret_cast<const float4*>(&qs[kq]);
        float4 q1 = *reinterpret_cast<const float4*>(&qs[kq + 4]);
        bfrag[kt][0] = f2b(fmaf(q0.x, wp0.x, wk0.x));
        bfrag[kt][1] = f2b(fmaf(q0.y, wp0.y, wk0.y));
        bfrag[kt][2] = f2b(fmaf(q0.z, wp0.z, wk0.z));
        bfrag[kt][3] = f2b(fmaf(q0.w, wp0.w, wk0.w));
        bfrag[kt][4] = f2b(fmaf(q1.x, wp1.x, wk1.x));
        bfrag[kt][5] = f2b(fmaf(q1.y, wp1.y, wk1.y));
        bfrag[kt][6] = f2b(fmaf(q1.z, wp1.z, wk1.z));
        bfrag[kt][7] = f2b(fmaf(q1.w, wp1.w, wk1.w));
    }

    // qconst partial: wave w covers d in [32w, 32w+32)
    {
        float s = 0.f;
        const int d0 = w << 5;
        #pragma unroll
        for (int dd = 0; dd < 32; ++dd)
            s = fmaf(qs[d0 + dd], Wqp[(d0 + dd) * 64 + lane], s);
        sp[w][lane] = s;
    }
    __syncthreads();   // B
    if (t < 64) qconst[t] = att_b1[t] + sp[0][t] + sp[1][t] + sp[2][t] + sp[3][t];
    __syncthreads();   // C

    // MFMA: acc init = qconst (broadcast over rows); wave w owns cols w*16..+15
    const float qc = qconst[(w << 4) + (lane & 15)];
    f32x4 acc[4];
    #pragma unroll
    for (int mt = 0; mt < 4; ++mt) {
        #pragma unroll
        for (int r = 0; r < 4; ++r) acc[mt][r] = qc;
    }
    #pragma unroll
    for (int mt = 0; mt < 4; ++mt) {
        const int row = (mt << 4) + (lane & 15);
        const int rbase = row << 8;
        const int swz = (row & 7) << 4;
        #pragma unroll
        for (int kt = 0; kt < 4; ++kt) {
            const int kbyte = (kt << 6) + ((lane >> 4) << 4);
            short8 a = *reinterpret_cast<const short8*>(
                reinterpret_cast<char*>(hist) + rbase + (kbyte ^ swz));
            acc[mt] = __builtin_amdgcn_mfma_f32_16x16x32_bf16(a, bfrag[kt], acc[mt], 0, 0, 0);
        }
    }

    // scores: relu(hidden) . w2, reduce over 16 cols then across waves
    {
        const float w2v = att_w2[(w << 4) + (lane & 15)];
        #pragma unroll
        for (int mt = 0; mt < 4; ++mt) {
            #pragma unroll
            for (int r = 0; r < 4; ++r) {
                float v = fmaxf(acc[mt][r], 0.f) * w2v;
                v += __shfl_xor(v, 1); v += __shfl_xor(v, 2);
                v += __shfl_xor(v, 4); v += __shfl_xor(v, 8);
                if ((lane & 15) == 0)
                    sp[w][(mt << 4) + ((lane >> 4) << 2) + r] = v;
            }
        }
    }
    __syncthreads();   // D

    // masked softmax over l (threads 0..63)
    if (t < 64) {
        float sc = sp[0][t] + sp[1][t] + sp[2][t] + sp[3][t] + att_b2[0];
        float s = (t < LL) ? ((seq_s[t] > 0) ? sc : -1e9f) : -INFINITY;
        float m = s;
        #pragma unroll
        for (int off = 32; off > 0; off >>= 1) m = fmaxf(m, __shfl_xor(m, off));
        float e = (t < LL) ? __expf(s - m) : 0.f;
        float sum = e;
        #pragma unroll
        for (int off = 32; off > 0; off >>= 1) sum += __shfl_xor(sum, off);
        if (t < LL) probs[t] = e / sum;
    }
    __syncthreads();   // E

    // interest: f32 re-gather (L1-hot rows), split over 256 threads
    {
        const int half = t >> 7, d = t & 127;
        const int l0 = half * 25;
        float s = 0.f;
        #pragma unroll 5
        for (int j = 0; j < 25; ++j) {
            const int l = l0 + j;
            s = fmaf(probs[l], emb_movie[(long)seq_s[l] * DE + d], s);
        }
        (&sp[0][0])[(half << 7) + d] = s;
    }
    __syncthreads();   // F

    if (t < 128) {
        const float* spf = &sp[0][0];
        xrow[256 + t] = spf[t] + spf[128 + t];
        xrow[t] = emb_user[(long)userId[b] * DE + t];
        xrow[128 + t] = qs[t];
        if (t < 8) xrow[384 + t] = dense[b * 8 + t];
    }
    __syncthreads();   // G

    // LayerNorm over 392
    float v0 = xrow[t];
    float v1 = (t < 136) ? xrow[256 + t] : 0.f;
    float s2 = v0 + v1, q2 = v0 * v0 + v1 * v1;
    #pragma unroll
    for (int off = 32; off > 0; off >>= 1) {
        s2 += __shfl_xor(s2, off);
        q2 += __shfl_xor(q2, off);
    }
    if (lane == 0) { sp[0][w] = s2; sp[1][w] = q2; }
    __syncthreads();
    if (t == 0) {
        float S = sp[0][0] + sp[0][1] + sp[0][2] + sp[0][3];
        float Q = sp[1][0] + sp[1][1] + sp[1][2] + sp[1][3];
        float mean = S / (float)DD;
        float var = Q / (float)DD - mean * mean;
        stats[0] = mean;
        stats[1] = rsqrtf(var + 1e-5f);
    }
    __syncthreads();
    const float mean = stats[0], inv = stats[1];
    const long base = (long)b * DD;
    float o0 = (v0 - mean) * inv * in_gamma[t] + in_beta[t];
    x0f[base + t] = o0; x0b[base + t] = f2b(o0);
    if (t < 136) {
        float o1 = (v1 - mean) * inv * in_gamma[256 + t] + in_beta[256 + t];
        x0f[base + 256 + t] = o1; x0b[base + 256 + t] = f2b(o1);
    }
}

// ---------------------------------------------------------------------------
// Generic bf16 MFMA GEMM: out = f(A[M,K](bf16) @ WT[N,K]^T(bf16) + bias)
// MODE 0: +bias ; 1: relu(+bias) ; 2: cross: out = x0*(acc+bias)+xin
// 64x64 tile, BK=64, 256 threads, wave w -> m-subtile w; z strides operands.
// ---------------------------------------------------------------------------
template<int MODE, int WF32, int WB16>
__global__ __launch_bounds__(256) void bgemm(
    const short* __restrict__ A, const short* __restrict__ WT,
    const float* __restrict__ bias,
    float* __restrict__ outF, short* __restrict__ outB,
    const float* __restrict__ x0, const float* __restrict__ xin,
    int M, int N, int K, long aZ, long wZ, long bZ, long oZ)
{
    __shared__ short As[64 * 64];   // swizzled: byte = r*128 + ((k*2)^((r&7)<<4))
    __shared__ short Bs[64 * 64];
    const int z = blockIdx.z;
    A += (long)z * aZ; WT += (long)z * wZ; bias += (long)z * bZ;
    const long oz = (long)z * oZ;

    const int t = threadIdx.x, w = t >> 6, lane = t & 63;
    const int m0 = blockIdx.y * 64, n0 = blockIdx.x * 64;
    const int sm = t >> 3, sk8 = (t & 7) << 3;   // staging: row, k-offset

    f32x4 acc[4];
    #pragma unroll
    for (int i = 0; i < 4; ++i) {
        #pragma unroll
        for (int r = 0; r < 4; ++r) acc[i][r] = 0.f;
    }

    for (int k0 = 0; k0 < K; k0 += 64) {
        #pragma unroll
        for (int i = 0; i < 2; ++i) {
            const int r = sm + i * 32;
            const int byte = (r << 7) + ((sk8 << 1) ^ ((r & 7) << 4));
            short8 av = {0, 0, 0, 0, 0, 0, 0, 0};
            if (k0 + sk8 < K)
                av = *reinterpret_cast<const short8*>(&A[(long)(m0 + r) * K + k0 + sk8]);
            *reinterpret_cast<short8*>(reinterpret_cast<char*>(As) + byte) = av;
            short8 bv = {0, 0, 0, 0, 0, 0, 0, 0};
            if (n0 + r < N && k0 + sk8 < K)
                bv = *reinterpret_cast<const short8*>(&WT[(long)(n0 + r) * K + k0 + sk8]);
            *reinterpret_cast<short8*>(reinterpret_cast<char*>(Bs) + byte) = bv;
        }
        __syncthreads();

        #pragma unroll
        for (int kt = 0; kt < 2; ++kt) {
            const int kbyte = (kt << 6) + ((lane >> 4) << 4);
            const int ar = (w << 4) + (lane & 15);
            short8 a = *reinterpret_cast<const short8*>(
                reinterpret_cast<char*>(As) + (ar << 7) + (kbyte ^ ((ar & 7) << 4)));
            #pragma unroll
            for (int nt = 0; nt < 4; ++nt) {
                const int br = (nt << 4) + (lane & 15);
                short8 bb = *reinterpret_cast<const short8*>(
                    reinterpret_cast<char*>(Bs) + (br << 7) + (kbyte ^ ((br & 7) << 4)));
                acc[nt] = __builtin_amdgcn_mfma_f32_16x16x32_bf16(a, bb, acc[nt], 0, 0, 0);
            }
        }
        __syncthreads();
    }

    #pragma unroll
    for (int nt = 0; nt < 4; ++nt) {
        const int col = n0 + (nt << 4) + (lane & 15);
        if (col < N) {
            const float bv = bias[col];
            #pragma unroll
            for (int r = 0; r < 4; ++r) {
                const int row = m0 + (w << 4) + ((lane >> 4) << 2) + r;
                float v = acc[nt][r] + bv;
                if (MODE == 1) v = fmaxf(v, 0.f);
                const long o = (long)row * N + col;
                if (MODE == 2) v = x0[o] * v + xin[o];
                if (WF32) outF[oz + o] = v;
                if (WB16) outB[oz + o] = f2b(v);
            }
        }
    }
}

// ---------------------------------------------------------------------------
// LayerNorm over 392 (block per row), f32 + bf16 outputs
// ---------------------------------------------------------------------------
__global__ __launch_bounds__(256) void ln_kernel(
    const float* __restrict__ in,
    const float* __restrict__ gamma, const float* __restrict__ beta,
    float* __restrict__ outF, short* __restrict__ outB)
{
    __shared__ float red[2][4];
    __shared__ float stats[2];
    const int b = blockIdx.x, t = threadIdx.x, lane = t & 63, w = t >> 6;
    const long base = (long)b * DD;
    float v0 = in[base + t];
    float v1 = (t < 136) ? in[base + 256 + t] : 0.f;
    float s = v0 + v1, q2 = v0 * v0 + v1 * v1;
    #pragma unroll
    for (int off = 32; off > 0; off >>= 1) {
        s += __shfl_xor(s, off);
        q2 += __shfl_xor(q2, off);
    }
    if (lane == 0) { red[0][w] = s; red[1][w] = q2; }
    __syncthreads();
    if (t == 0) {
        float S = red[0][0] + red[0][1] + red[0][2] + red[0][3];
        float Q = red[1][0] + red[1][1] + red[1][2] + red[1][3];
        float mean = S / (float)DD;
        float var = Q / (float)DD - mean * mean;
        stats[0] = mean;
        stats[1] = rsqrtf(var + 1e-5f);
    }
    __syncthreads();
    const float mean = stats[0], inv = stats[1];
    float o0 = (v0 - mean) * inv * gamma[t] + beta[t];
    outF[base + t] = o0; outB[base + t] = f2b(o0);
    if (t < 136) {
        float o1 = (v1 - mean) * inv * gamma[256 + t] + beta[256 + t];
        outF[base + 256 + t] = o1; outB[base + 256 + t] = f2b(o1);
    }
}

// ---------------------------------------------------------------------------
// K3: gates (from x f32) + expert-head dots (from h1 bf16 via hw2) + mix.
// One wave per row, 4 rows/block.
// ---------------------------------------------------------------------------
__global__ __launch_bounds__(256) void final_kernel(
    const float* __restrict__ x, const short* __restrict__ h1,
    const float* __restrict__ hw2, const float* __restrict__ hc,
    const float* __restrict__ gate_w, const float* __restrict__ gate_b,
    const float* __restrict__ head_b, float* __restrict__ out)
{
    const int t = threadIdx.x, lane = t & 63, w = t >> 6;
    const int b = blockIdx.x * 4 + w;
    const float* xr = x + (long)b * DD;

    float xv[7];
    #pragma unroll
    for (int i = 0; i < 7; ++i) {
        int d = lane + (i << 6);
        xv[i] = (d < DD) ? xr[d] : 0.f;
    }

    // gate logits [t][e], 8 values
    float gl[8] = {0.f, 0.f, 0.f, 0.f, 0.f, 0.f, 0.f, 0.f};
    #pragma unroll
    for (int i = 0; i < 7; ++i) {
        int d = lane + (i << 6);
        if (d < DD) {
            float4 g0 = *reinterpret_cast<const float4*>(&gate_w[d << 2]);
            float4 g1 = *reinterpret_cast<const float4*>(&gate_w[1568 + (d << 2)]);
            gl[0] = fmaf(xv[i], g0.x, gl[0]); gl[1] = fmaf(xv[i], g0.y, gl[1]);
            gl[2] = fmaf(xv[i], g0.z, gl[2]); gl[3] = fmaf(xv[i], g0.w, gl[3]);
            gl[4] = fmaf(xv[i], g1.x, gl[4]); gl[5] = fmaf(xv[i], g1.y, gl[5]);
            gl[6] = fmaf(xv[i], g1.z, gl[6]); gl[7] = fmaf(xv[i], g1.w, gl[7]);
        }
    }

    // expert-head dots: ed[e] (task0), ed[4+e] (task1)
    float ed[8];
    #pragma unroll
    for (int e = 0; e < 4; ++e) {
        short4v hv = *reinterpret_cast<const short4v*>(
            &h1[((long)e * BB + b) * HH1 + (lane << 2)]);
        const float* hwp = &hw2[(((e << 8) + (lane << 2))) << 1];
        float4 w01 = *reinterpret_cast<const float4*>(hwp);      // k0t0 k0t1 k1t0 k1t1
        float4 w23 = *reinterpret_cast<const float4*>(hwp + 4);  // k2t0 k2t1 k3t0 k3t1
        float h0 = b2f(hv[0]), h1f = b2f(hv[1]), h2 = b2f(hv[2]), h3 = b2f(hv[3]);
        ed[e]     = fmaf(h0, w01.x, fmaf(h1f, w01.z, fmaf(h2, w23.x, h3 * w23.z)));
        ed[4 + e] = fmaf(h0, w01.y, fmaf(h1f, w01.w, fmaf(h2, w23.y, h3 * w23.w)));
    }

    #pragma unroll
    for (int v = 0; v < 8; ++v) {
        #pragma unroll
        for (int off = 32; off > 0; off >>= 1) {
            gl[v] += __shfl_xor(gl[v], off);
            ed[v] += __shfl_xor(ed[v], off);
        }
    }

    if (lane == 0) {
        // per-task softmax over 4 experts + combine
        float res[2];
        #pragma unroll
        for (int tt = 0; tt < 2; ++tt) {
            float lv[4], m = -1e30f;
            #pragma unroll
            for (int e = 0; e < 4; ++e) {
                lv[e] = gl[tt * 4 + e] + gate_b[tt * 4 + e];
                m = fmaxf(m, lv[e]);
            }
            float sum = 0.f, acc = 0.f;
            #pragma unroll
            for (int e = 0; e < 4; ++e) { lv[e] = __expf(lv[e] - m); sum += lv[e]; }
            #pragma unroll
            for (int e = 0; e < 4; ++e)
                acc = fmaf(lv[e], ed[tt * 4 + e] + hc[e * 2 + tt], acc);
            res[tt] = head_b[tt] + acc / sum;
        }
        out[b] = res[0];
        out[BB + b] = res[1];
    }
}

// ---------------------------------------------------------------------------
extern "C" void kernel_launch(void* const* d_in, const int* in_sizes, int n_in,
                              void* d_out, int out_size, void* d_ws, size_t ws_size,
                              hipStream_t stream) {
    const int*   userId    = (const int*)d_in[0];
    const int*   movieId   = (const int*)d_in[1];
    const int*   seq       = (const int*)d_in[2];
    const float* dense     = (const float*)d_in[3];
    const float* emb_user  = (const float*)d_in[4];
    const float* emb_movie = (const float*)d_in[5];
    const float* att_w1    = (const float*)d_in[6];
    const float* att_b1    = (const float*)d_in[7];
    const float* att_w2    = (const float*)d_in[8];
    const float* att_b2    = (const float*)d_in[9];
    const float* in_gamma  = (const float*)d_in[10];
    const float* in_beta   = (const float*)d_in[11];
    const float* cr_gamma  = (const float*)d_in[12];
    const float* cr_beta   = (const float*)d_in[13];
    const float* cross_W   = (const float*)d_in[14];
    const float* cross_b   = (const float*)d_in[15];
    const float* exp_w1    = (const float*)d_in[16];
    const float* exp_b1    = (const float*)d_in[17];
    const float* exp_w2    = (const float*)d_in[18];
    const float* exp_b2    = (const float*)d_in[19];
    const float* gate_w    = (const float*)d_in[20];
    const float* gate_b    = (const float*)d_in[21];
    const float* head_w    = (const float*)d_in[22];
    const float* head_b    = (const float*)d_in[23];
    float* outp = (float*)d_out;

    char* p = (char*)d_ws;
    auto alloc = [&](size_t bytes) -> char* {
        char* r = p; p += (bytes + 255) & ~(size_t)255; return r;
    };
    float* Wqp = (float*)alloc(8192 * 4);
    float* WkF = (float*)alloc(8192 * 4);
    float* WpF = (float*)alloc(8192 * 4);
    float* hw2 = (float*)alloc(2048 * 4);
    float* hc  = (float*)alloc(8 * 4);
    short* WTc = (short*)alloc((size_t)3 * 392 * 392 * 2);
    short* WT1 = (short*)alloc((size_t)4 * 256 * 392 * 2);
    float* x0f = (float*)alloc((size_t)BB * DD * 4);
    short* x0b = (short*)alloc((size_t)BB * DD * 2);
    float* xAf = (float*)alloc((size_t)BB * DD * 4);
    short* xAb = (short*)alloc((size_t)BB * DD * 2);
    float* xBf = (float*)alloc((size_t)BB * DD * 4);
    short* xBb = (short*)alloc((size_t)BB * DD * 2);
    short* h1b = (short*)alloc((size_t)4 * BB * HH1 * 2);

    prep_wqp<<<32, 256, 0, stream>>>(att_w1, Wqp);
    prep_wkwp<<<32, 256, 0, stream>>>(att_w1, WkF, WpF);
    trans_kernel<<<dim3(601, 3), 256, 0, stream>>>(cross_W, WTc, 392, 392);
    trans_kernel<<<dim3(392, 4), 256, 0, stream>>>(exp_w1, WT1, 392, 256);
    prep_hw2<<<4, 256, 0, stream>>>(exp_w2, exp_b2, head_w, hw2, hc);

    attn_kernel<<<BB, 256, 0, stream>>>(userId, movieId, seq, dense,
                                        emb_user, emb_movie, Wqp, WkF, WpF,
                                        att_b1, att_w2, att_b2,
                                        in_gamma, in_beta, x0f, x0b);

    // CrossNetV2
    dim3 gc(7, BB / 64, 1);
    bgemm<2, 1, 1><<<gc, 256, 0, stream>>>(x0b, WTc, cross_b, xAf, xAb,
                                           x0f, x0f, BB, DD, DD, 0, 0, 0, 0);
    bgemm<2, 1, 1><<<gc, 256, 0, stream>>>(xAb, WTc + 392 * 392, cross_b + 392, xBf, xBb,
                                           x0f, xAf, BB, DD, DD, 0, 0, 0, 0);
    bgemm<2, 1, 0><<<gc, 256, 0, stream>>>(xBb, WTc + 2 * 392 * 392, cross_b + 784, xAf, nullptr,
                                           x0f, xBf, BB, DD, DD, 0, 0, 0, 0);

    // LN2: xAf -> xBf (+bf16)
    ln_kernel<<<BB, 256, 0, stream>>>(xAf, cr_gamma, cr_beta, xBf, xBb);

    // Experts layer 1 only: h1 = relu(x @ w1 + b1)  [E][B][256] bf16
    bgemm<1, 0, 1><<<dim3(HH1 / 64, BB / 64, 4), 256, 0, stream>>>(
        xBb, WT1, exp_b1, nullptr, h1b, nullptr, nullptr,
        BB, HH1, DD, 0, (long)HH1 * DD, HH1, (long)BB * HH1);

    // gates + expert-head dots + mix -> logits [2][B]
    final_kernel<<<BB / 4, 256, 0, stream>>>(xBf, h1b, hw2, hc,
                                             gate_w, gate_b, head_b, outp);

    (void)in_sizes; (void)n_in; (void)out_size; (void)ws_size;
}